// Round 8
// baseline (12218.797 us; speedup 1.0000x reference)
//
#include <hip/hip_runtime.h>

#define B_TOT 1024
#define L_T   100
#define DIN   32
#define HID   128
#define DOUT  32
#define BT    16      // batch rows per block (= MFMA M)
#define NBLK  64      // 1024 / 16
#define NTHREADS 1024 // 16 waves

typedef _Float16 half8 __attribute__((ext_vector_type(8)));
typedef float    f32x4 __attribute__((ext_vector_type(4)));

// XOR-swizzled index into a [16][128] f16 LDS tile (bank-conflict-free b128 reads)
#define SWZ(r,c) (((r) << 7) + ((c) ^ (((r) & 7) << 3)))

__device__ __forceinline__ float fast_exp2(float x){
#if __has_builtin(__builtin_amdgcn_exp2f)
  return __builtin_amdgcn_exp2f(x);
#else
  float r; asm("v_exp_f32 %0, %1\n\ts_nop 1" : "=v"(r) : "v"(x)); return r;
#endif
}
__device__ __forceinline__ float fast_rcp(float x){
#if __has_builtin(__builtin_amdgcn_rcpf)
  return __builtin_amdgcn_rcpf(x);
#else
  float r; asm("v_rcp_f32 %0, %1\n\ts_nop 1" : "=v"(r) : "v"(x)); return r;
#endif
}
__device__ __forceinline__ float fast_tanh(float x){
  float e = fast_exp2(x * 2.885390081777926f);  // 2*log2(e)
  return 1.0f - 2.0f * fast_rcp(e + 1.0f);
}

// Reorder [N][K] f32 row-major weights into fragment-ready f16 tiles:
// dst[((tile*(K/32)+k0)*64 + lane)*8 + ki], lane = (n&15) + 16*((k>>3)&3)
__global__ void reorder_w(const float* __restrict__ src, _Float16* __restrict__ dst,
                          int N, int K){
  int id = blockIdx.x * 256 + threadIdx.x;
  if (id >= N * K) return;
  int n = id / K, k = id - n * K;
  int tile = n >> 4, nl = n & 15;
  int kq = (k >> 3) & 3, k0 = k >> 5, ki = k & 7;
  int lane = nl + (kq << 4);
  int K32 = K >> 5;
  dst[(((tile * K32 + k0) << 6) + lane) * 8 + ki] = (_Float16)src[id];
}

// async global->LDS, 16B/lane. LDS dest is wave-uniform base (HW adds lane*16);
// global src is per-lane. Builtin (not asm) so the compiler models vmcnt.
__device__ __forceinline__ void gload_lds16(const _Float16* g, _Float16* l){
  __builtin_amdgcn_global_load_lds(
      (const __attribute__((address_space(1))) void*)g,
      (__attribute__((address_space(3))) void*)l, 16, 0, 0);
}

__global__ __launch_bounds__(NTHREADS) void cde_main(
    const float* __restrict__ coeffs, const float* __restrict__ times,
    const float* __restrict__ init_b, const float* __restrict__ fb0,
    const float* __restrict__ fb1,    const float* __restrict__ fb2,
    const float* __restrict__ fbf,    const float* __restrict__ dec_b,
    const _Float16* __restrict__ W,   float* __restrict__ out)
{
  __shared__ _Float16 bufA[BT*HID];      // ping-pong activation buffers (f16, swizzled)
  __shared__ _Float16 bufB[BT*HID];
  __shared__ float    dzs[BT][HID];      // vf output (also init z0 scratch)
  __shared__ float    dxs[BT][DIN];      // dX/dt for current interval
  __shared__ _Float16 fbfs[HID*DIN];     // fwf bias (f16: |err|~4e-5, negligible)
  __shared__ _Float16 win[16][2][2048];  // per-wave 2-tile Wf DMA window (128 KiB)
  // total LDS = 4096+4096+8192+2048+8192+131072 = 157,696 B  (<160 KiB)

  const int tid  = threadIdx.x;
  const int lane = tid & 63;
  const int w    = tid >> 6;   // wave 0..15
  const int cl   = lane & 15;
  const int g    = lane >> 4;
  const int b0   = blockIdx.x * BT;
  const int r0   = tid >> 7, c0 = tid & 127, r1 = r0 + 8;  // combine mapping

  const _Float16* W0 = W;
  const _Float16* W1 = W + 16384;
  const _Float16* W2 = W + 32768;
  const _Float16* Wf = W + 49152;   // fwf: 4096x128 -> 256 tiles
  const _Float16* Wi = W + 573440;  // init_w
  const _Float16* Wd = W + 577536;  // dec_w
  const _Float16* Wfw = Wf + w * 16 * 2048;  // this wave's 16 tiles (64 KiB)

  // lgkm-only barrier (two-sided clobbers + sched pins). vmcnt NOT drained:
  // cross-wave deps are LDS-only; in-flight DMAs write wave-PRIVATE window
  // slots, so they may legally span barriers.
  auto bar = [&]{
    __builtin_amdgcn_sched_barrier(0);
    asm volatile("s_waitcnt lgkmcnt(0)" ::: "memory");
    __builtin_amdgcn_s_barrier();
    __builtin_amdgcn_sched_barrier(0);
    asm volatile("" ::: "memory");
  };

#define DMA_TILE(SLOT, IDX) {                                   \
    const _Float16* _g = Wfw + (IDX)*2048 + lane*8;             \
    _Float16* _l = &win[w][SLOT][0];                            \
    gload_lds16(_g,        _l);                                 \
    gload_lds16(_g +  512, _l +  512);                          \
    gload_lds16(_g + 1024, _l + 1024);                          \
    gload_lds16(_g + 1536, _l + 1536); }

  // fbf biases -> LDS f16 (once)
  for (int i = tid; i < HID*DIN; i += NTHREADS) fbfs[i] = (_Float16)fbf[i];

  // ---- init: z0 = coeffs[:,0,:] @ init_w.T + init_b ----
  if (tid < BT*DIN){
    int r = tid >> 5, d = tid & 31;
    bufB[SWZ(r, d)] = (_Float16)coeffs[(b0 + r)*(L_T*DIN) + d];
  }
  bar();
  if (w < 8){
    f32x4 acc = {0.f,0.f,0.f,0.f};
    half8 a = *(const half8*)(bufB + SWZ(cl, 8*g));
    half8 b = *(const half8*)(Wi + (w*64 + lane)*8);
    acc = __builtin_amdgcn_mfma_f32_16x16x32_f16(a, b, acc, 0, 0, 0);
    float bn = init_b[w*16 + cl];
#pragma unroll
    for (int r = 0; r < 4; ++r){
      float v = acc[r] + bn;
      dzs[4*g + r][w*16 + cl] = v;                  // f32 z0 -> combine threads
      bufA[SWZ(4*g + r, w*16 + cl)] = (_Float16)v;  // f16 stage input
    }
  }
  bar();
  float zf0 = dzs[r0][c0], zf1 = dzs[r1][c0];  // f32 master state in regs
  float ka0 = 0.f, ka1 = 0.f;                  // RK4 k-accumulator in regs

// Dense HID->HID; B-fragments from L2-resident weights (compiler-modeled vmcnt).
#define DENSE(IN, OB, WT, BIAS) {                                          \
    f32x4 acc = {0.f,0.f,0.f,0.f};                                         \
    _Pragma("unroll")                                                      \
    for (int kq = 0; kq < 4; ++kq){                                        \
      half8 a = *(const half8*)((IN) + SWZ(cl, kq*32 + 8*g));              \
      half8 b = *(const half8*)((WT) + ((w*4 + kq)*64 + lane)*8);          \
      acc = __builtin_amdgcn_mfma_f32_16x16x32_f16(a, b, acc, 0,0,0);}     \
    float bn = (BIAS)[w*16 + cl];                                          \
    _Pragma("unroll")                                                      \
    for (int r = 0; r < 4; ++r)                                            \
      (OB)[SWZ(4*g + r, w*16 + cl)] = (_Float16)fast_tanh(acc[r] + bn); }

#define DECODER(TS) {                                                      \
    int dw = w - 14;                                                       \
    f32x4 acc = {0.f,0.f,0.f,0.f};                                         \
    _Pragma("unroll")                                                      \
    for (int kq = 0; kq < 4; ++kq){                                        \
      half8 a = *(const half8*)(bufA + SWZ(cl, kq*32 + 8*g));              \
      half8 b = *(const half8*)(Wd + ((dw*4 + kq)*64 + lane)*8);           \
      acc = __builtin_amdgcn_mfma_f32_16x16x32_f16(a, b, acc, 0,0,0);}     \
    float bn = dec_b[dw*16 + cl];                                          \
    _Pragma("unroll")                                                      \
    for (int r = 0; r < 4; ++r)                                            \
      out[(b0 + 4*g + r)*(L_T*DOUT) + (TS)*DOUT + dw*16 + cl] = acc[r] + bn; }

  for (int t = 0; t < L_T - 1; ++t){
    // decoder(t) on waves 14/15: bufA (=z_t) is not rewritten until dense1,
    // two barriers after these ds_reads complete (at this wave's bar()).
    if (w >= 14) DECODER(t)

    float dt = times[t+1] - times[t];
    if (tid < BT*DIN){
      int r = tid >> 5, d = tid & 31;
      const float* cp = coeffs + (b0 + r)*(L_T*DIN) + t*DIN + d;
      dxs[r][d] = (cp[DIN] - cp[0]) / dt;
    }
    bar();

    for (int s = 0; s < 4; ++s){
      // dense0 + prime the window with tiles 0,1 (DMAs fly across barriers)
      if (w < 8) DENSE(bufA, bufB, W0, fb0)
      DMA_TILE(0, 0)
      DMA_TILE(1, 1)
      bar();
      if (w < 8) DENSE(bufB, bufA, W1, fb1)
      bar();
      if (w < 8) DENSE(bufA, bufB, W2, fb2)
      bar();

      // ---- biglayer: 16 waves, 16 tiles each, counted-vmcnt LDS pipeline
      {
        half8 af[4];
#pragma unroll
        for (int kq = 0; kq < 4; ++kq)
          af[kq] = *(const half8*)(bufB + SWZ(cl, kq*32 + 8*g));
        float p[4];
#pragma unroll
        for (int u = 0; u < 16; ++u){
          // tile u ready (leave tile u+1's 4 DMAs in flight); u=15: drain
          if (u < 15) asm volatile("s_waitcnt vmcnt(4)" ::: "memory");
          else        asm volatile("s_waitcnt vmcnt(0)" ::: "memory");
          __builtin_amdgcn_sched_barrier(0);
          const _Float16* wp = &win[w][u & 1][0];
          half8 b0f = *(const half8*)(wp + lane*8);
          half8 b1f = *(const half8*)(wp +  512 + lane*8);
          half8 b2f = *(const half8*)(wp + 1024 + lane*8);
          half8 b3f = *(const half8*)(wp + 1536 + lane*8);
          float bn = (float)fbfs[(w*16 + u)*16 + cl];
          float dxv[4];
#pragma unroll
          for (int r = 0; r < 4; ++r)
            dxv[r] = dxs[4*g + r][(u & 1)*16 + cl];
          // drain LDS reads BEFORE reusing the slot (WAR vs incoming DMA)
          asm volatile("s_waitcnt lgkmcnt(0)" ::: "memory");
          __builtin_amdgcn_sched_barrier(0);
          if (u < 14) DMA_TILE(u & 1, u + 2)
          __builtin_amdgcn_sched_barrier(0);
          f32x4 acc = {0.f,0.f,0.f,0.f};
          acc = __builtin_amdgcn_mfma_f32_16x16x32_f16(af[0], b0f, acc, 0,0,0);
          acc = __builtin_amdgcn_mfma_f32_16x16x32_f16(af[1], b1f, acc, 0,0,0);
          acc = __builtin_amdgcn_mfma_f32_16x16x32_f16(af[2], b2f, acc, 0,0,0);
          acc = __builtin_amdgcn_mfma_f32_16x16x32_f16(af[3], b3f, acc, 0,0,0);
          if ((u & 1) == 0){
#pragma unroll
            for (int r = 0; r < 4; ++r) p[r] = fast_tanh(acc[r] + bn) * dxv[r];
          } else {
#pragma unroll
            for (int r = 0; r < 4; ++r) p[r] += fast_tanh(acc[r] + bn) * dxv[r];
#pragma unroll
            for (int m = 1; m < 16; m <<= 1){
#pragma unroll
              for (int r = 0; r < 4; ++r) p[r] += __shfl_xor(p[r], m, 64);
            }
            if (cl == 0){
#pragma unroll
              for (int r = 0; r < 4; ++r) dzs[4*g + r][w*8 + (u >> 1)] = p[r];
            }
          }
        }
      }
      bar();

      // ---- RK4 combine: state in registers (2 elems/thread)
      {
        float kv0 = dzs[r0][c0], kv1 = dzs[r1][c0];
        float nin0, nin1;
        if (s == 0){ ka0 = kv0;        ka1 = kv1;        nin0 = zf0 + 0.5f*dt*kv0; nin1 = zf1 + 0.5f*dt*kv1; }
        else if (s == 1){ ka0 += 2.f*kv0; ka1 += 2.f*kv1; nin0 = zf0 + 0.5f*dt*kv0; nin1 = zf1 + 0.5f*dt*kv1; }
        else if (s == 2){ ka0 += 2.f*kv0; ka1 += 2.f*kv1; nin0 = zf0 + dt*kv0;      nin1 = zf1 + dt*kv1; }
        else { zf0 += (dt*(1.f/6.f))*(ka0 + kv0); zf1 += (dt*(1.f/6.f))*(ka1 + kv1);
               nin0 = zf0; nin1 = zf1; }
        bufA[SWZ(r0, c0)] = (_Float16)nin0;
        bufA[SWZ(r1, c0)] = (_Float16)nin1;
      }
      bar();
    }
  }
  if (w >= 14) DECODER(L_T - 1)
}

extern "C" void kernel_launch(void* const* d_in, const int* in_sizes, int n_in,
                              void* d_out, int out_size, void* d_ws, size_t ws_size,
                              hipStream_t stream){
  const float* coeffs = (const float*)d_in[0];
  const float* times  = (const float*)d_in[1];
  const float* init_w = (const float*)d_in[2];
  const float* init_b = (const float*)d_in[3];
  const float* fw0    = (const float*)d_in[4];
  const float* fb0    = (const float*)d_in[5];
  const float* fw1    = (const float*)d_in[6];
  const float* fb1    = (const float*)d_in[7];
  const float* fw2    = (const float*)d_in[8];
  const float* fb2    = (const float*)d_in[9];
  const float* fwf    = (const float*)d_in[10];
  const float* fbf    = (const float*)d_in[11];
  const float* dec_w  = (const float*)d_in[12];
  const float* dec_b  = (const float*)d_in[13];
  _Float16* W = (_Float16*)d_ws;

  hipLaunchKernelGGL(reorder_w, dim3(64),   dim3(256), 0, stream, fw0, W,          128, 128);
  hipLaunchKernelGGL(reorder_w, dim3(64),   dim3(256), 0, stream, fw1, W + 16384,  128, 128);
  hipLaunchKernelGGL(reorder_w, dim3(64),   dim3(256), 0, stream, fw2, W + 32768,  128, 128);
  hipLaunchKernelGGL(reorder_w, dim3(2048), dim3(256), 0, stream, fwf, W + 49152,  4096, 128);
  hipLaunchKernelGGL(reorder_w, dim3(16),   dim3(256), 0, stream, init_w, W + 573440, 128, 32);
  hipLaunchKernelGGL(reorder_w, dim3(16),   dim3(256), 0, stream, dec_w,  W + 577536,  32, 128);

  hipLaunchKernelGGL(cde_main, dim3(NBLK), dim3(NTHREADS), 0, stream,
                     coeffs, times, init_b, fb0, fb1, fb2, fbf, dec_b,
                     W, (float*)d_out);
}